// Round 11
// baseline (605.112 us; speedup 1.0000x reference)
//
#include <hip/hip_runtime.h>
#include <stdint.h>

#define T_TOK 1024
#define HID   2048
#define NE    8
#define INTER 5632
#define I2    11264
#define BK    64
#define MAXT  18     // worst-case sum ceil(c64/256) over experts
#define RMAX  2560
#define KCH   1408   // INTER/4, GEMM2 K-split chunk

typedef __bf16 bf16x8 __attribute__((ext_vector_type(8)));
typedef __bf16 bf16x4 __attribute__((ext_vector_type(4)));
typedef float  f32x4  __attribute__((ext_vector_type(4)));
typedef unsigned short u16;
typedef u16 u16x8 __attribute__((ext_vector_type(8)));

// ws layout: mi/mf meta in [0,64KB); act (bf16, RMAX x INTER) at byte 65536;
// hpk (bf16, T_TOK x HID) at byte 33554432.

__device__ __forceinline__ int swz(int row, int cb) {
    return row * 128 + (cb ^ ((row & 7) << 4));
}

__device__ __forceinline__ bf16x4 cvt4(float4 v) {
    bf16x4 r;
    r[0] = (__bf16)v.x; r[1] = (__bf16)v.y; r[2] = (__bf16)v.z; r[3] = (__bf16)v.w;
    return r;
}

__global__ __launch_bounds__(256) void moe_pack(const float* __restrict__ h,
                                                u16* __restrict__ hpk) {
    int i = blockIdx.x * blockDim.x + threadIdx.x;
    float4 a = ((const float4*)h)[2 * i];
    float4 b = ((const float4*)h)[2 * i + 1];
    bf16x8 o;
    o[0] = (__bf16)a.x; o[1] = (__bf16)a.y; o[2] = (__bf16)a.z; o[3] = (__bf16)a.w;
    o[4] = (__bf16)b.x; o[5] = (__bf16)b.y; o[6] = (__bf16)b.z; o[7] = (__bf16)b.w;
    ((bf16x8*)hpk)[i] = o;
}

__global__ void moe_router(const float* __restrict__ logits,
                           int* __restrict__ mi, float* __restrict__ mf) {
    int t = blockIdx.x * blockDim.x + threadIdx.x;
    if (t >= T_TOK) return;
    float l[NE];
#pragma unroll
    for (int i = 0; i < NE; ++i) l[i] = logits[t * NE + i];
    int e0 = 0; float v0 = l[0];
#pragma unroll
    for (int i = 1; i < NE; ++i) if (l[i] > v0) { v0 = l[i]; e0 = i; }
    int e1 = -1; float v1 = -3.4e38f;
#pragma unroll
    for (int i = 0; i < NE; ++i) if (i != e0 && l[i] > v1) { v1 = l[i]; e1 = i; }
    float ex = __expf(v1 - v0);
    float s  = 1.f + ex;
    mi[256 + 2 * t]     = e0;
    mi[256 + 2 * t + 1] = e1;
    mf[8192 + 2 * t]     = 1.f / s;
    mf[8192 + 2 * t + 1] = ex / s;
    atomicAdd(&mi[e0], 1);
    atomicAdd(&mi[e1], 1);
}

__global__ void moe_plan(int* __restrict__ mi) {
    int tid = threadIdx.x;
    if (tid == 0) {
        int off = 0, nt = 0;
        for (int e = 0; e < NE; ++e) {
            int c = mi[e];
            mi[24 + e] = off;
            int c64 = ((c + 63) >> 6) << 6;          // 64-padded slot region
            int ntile = (c64 + 255) >> 8;            // 256-row tiles
            for (int j = 0; j < ntile; ++j) {
                mi[32 + 2 * nt]     = e;
                mi[32 + 2 * nt + 1] = off + j * 256;
                ++nt;
            }
            off += c64;
            mi[8 + e] = 0;
        }
        mi[16] = nt;
    }
    for (int i = tid; i < RMAX; i += blockDim.x) mi[2560 + i] = -1;
}

__global__ void moe_scatter(int* __restrict__ mi, float* __restrict__ mf) {
    int t = blockIdx.x * blockDim.x + threadIdx.x;
    if (t >= T_TOK) return;
    int e0 = mi[256 + 2 * t], e1 = mi[256 + 2 * t + 1];
    float w0 = mf[8192 + 2 * t], w1 = mf[8192 + 2 * t + 1];
    int p0 = atomicAdd(&mi[8 + e0], 1);
    int s0 = mi[24 + e0] + p0;
    mi[2560 + s0] = t; mf[5632 + s0] = w0;
    int p1 = atomicAdd(&mi[8 + e1], 1);
    int s1 = mi[24 + e1] + p1;
    mi[2560 + s1] = t; mf[5632 + s1] = w1;
}

// ---- GEMM1: 256x(64g+64u) tile per block, 512 threads, 2-phase pipeline ----
// merged LDS: As @0 (32KB bf16), Bg @32768 (8KB), Bu @40960 (8KB), toks @49152

#define G1_LOAD(K0)                                                          \
    _Pragma("unroll")                                                        \
    for (int it = 0; it < 4; ++it) {                                         \
        u16x8 z = {};                                                        \
        raa[it] = ap1[it] ? *(const u16x8*)(ap1[it] + (K0)) : z;             \
    }                                                                        \
    _Pragma("unroll")                                                        \
    for (int it = 0; it < 2; ++it) {                                         \
        rg[it] = *(const float4*)(bgp[it] + (K0));                           \
        ru[it] = *(const float4*)(bup[it] + (K0));                           \
    }

#define G1_WRITE()                                                           \
    _Pragma("unroll")                                                        \
    for (int it = 0; it < 4; ++it)                                           \
        *(u16x8*)(As + swz((tid >> 3) + it * 64, acb)) = raa[it];            \
    _Pragma("unroll")                                                        \
    for (int it = 0; it < 2; ++it) {                                         \
        *(bf16x4*)(Bgs + swz(sr + it * 32, scb)) = cvt4(rg[it]);             \
        *(bf16x4*)(Bus + swz(sr + it * 32, scb)) = cvt4(ru[it]);             \
    }

#define G1_MFMA()                                                            \
    _Pragma("unroll")                                                        \
    for (int kk = 0; kk < 2; ++kk) {                                         \
        int kb = kk * 64 + lk * 16;                                          \
        bf16x8 a0 = *(const bf16x8*)(As + swz(w * 32 + lrow, kb));           \
        bf16x8 a1 = *(const bf16x8*)(As + swz(w * 32 + 16 + lrow, kb));      \
        _Pragma("unroll")                                                    \
        for (int fn = 0; fn < 4; ++fn) {                                     \
            bf16x8 bg = *(const bf16x8*)(Bgs + swz(fn * 16 + lrow, kb));     \
            bf16x8 bu = *(const bf16x8*)(Bus + swz(fn * 16 + lrow, kb));     \
            accg[0][fn] = __builtin_amdgcn_mfma_f32_16x16x32_bf16(a0, bg, accg[0][fn], 0, 0, 0); \
            accg[1][fn] = __builtin_amdgcn_mfma_f32_16x16x32_bf16(a1, bg, accg[1][fn], 0, 0, 0); \
            accu[0][fn] = __builtin_amdgcn_mfma_f32_16x16x32_bf16(a0, bu, accu[0][fn], 0, 0, 0); \
            accu[1][fn] = __builtin_amdgcn_mfma_f32_16x16x32_bf16(a1, bu, accu[1][fn], 0, 0, 0); \
        }                                                                    \
    }

__global__ __launch_bounds__(512) void moe_gemm1(
        const u16* __restrict__ hpk, const float* __restrict__ w13,
        const int* __restrict__ mi, u16* __restrict__ act) {
    const int tj = blockIdx.x, ct = blockIdx.y;   // tj-fastest
    if (tj >= mi[16]) return;
    const int e = mi[32 + 2 * tj], row_base = mi[32 + 2 * tj + 1];
    const int* rowtok = mi + 2560;
    const int limit = mi[24 + e] + (((mi[e] + 63) >> 6) << 6);

    __shared__ __align__(16) char smem[50176];
    char* As  = smem;
    char* Bgs = smem + 32768;
    char* Bus = smem + 40960;
    int*  toks = (int*)(smem + 49152);

    const int tid = threadIdx.x;
    const int w = tid >> 6, lane = tid & 63;
    const int lrow = lane & 15, lk = lane >> 4;

    const int sr  = tid >> 4;          // B staging: 0..31
    const int sc  = (tid & 15) * 4;
    const int scb = (tid & 15) * 8;
    const int acb = (tid & 7) * 16;    // A staging byte col

    if (tid < 256) {
        int idx = row_base + tid;
        toks[tid] = (idx < limit) ? rowtok[idx] : -1;
    }
    __syncthreads();

    const u16* ap1[4];
#pragma unroll
    for (int it = 0; it < 4; ++it) {
        int tok = toks[(tid >> 3) + it * 64];
        ap1[it] = (tok >= 0) ? hpk + (size_t)tok * HID + (tid & 7) * 8 : nullptr;
    }
    const float* bg_base = w13 + ((size_t)e * I2 + (size_t)ct * 64) * HID;
    const float* bu_base = bg_base + (size_t)INTER * HID;
    const float* bgp[2];
    const float* bup[2];
#pragma unroll
    for (int it = 0; it < 2; ++it) {
        bgp[it] = bg_base + (size_t)(sr + it * 32) * HID + sc;
        bup[it] = bu_base + (size_t)(sr + it * 32) * HID + sc;
    }

    f32x4 accg[2][4] = {}, accu[2][4] = {};
    u16x8 raa[4]; float4 rg[2], ru[2];

    G1_LOAD(0)
    G1_WRITE()
    __syncthreads();
    for (int k0 = BK; k0 <= HID; k0 += BK) {
        const bool more = k0 < HID;
        if (more) { G1_LOAD(k0) }
        G1_MFMA()
        __syncthreads();
        if (more) { G1_WRITE() __syncthreads(); }
    }

    const size_t actbase = (size_t)row_base * INTER + (size_t)ct * 64;
#pragma unroll
    for (int fm = 0; fm < 2; ++fm)
#pragma unroll
    for (int fn = 0; fn < 4; ++fn)
#pragma unroll
    for (int j = 0; j < 4; ++j) {
        int row = w * 32 + fm * 16 + lk * 4 + j;
        int col = fn * 16 + lrow;
        if (toks[row] >= 0) {
            float g = accg[fm][fn][j], u = accu[fm][fn][j];
            float a = g / (1.f + __expf(-g)) * u;
            ((__bf16*)act)[actbase + (size_t)row * INTER + col] = (__bf16)a;
        }
    }
}

// ---- GEMM2: 256x128 tile per (tj, ct, kz) block, 512 threads, K-split z=4 --
// merged LDS: As2 @0 (32KB bf16), Bs2 @32768 (16KB bf16)
// waves: wm = w>>1 (4, 64 rows each), wn = w&1 (2, 64 cols each); acc[4][4]

#define G2_LOAD(K0)                                                          \
    _Pragma("unroll")                                                        \
    for (int it = 0; it < 4; ++it) {                                         \
        u16x8 z = {};                                                        \
        raa[it] = ap2[it] ? *(const u16x8*)(ap2[it] + (K0)) : z;             \
    }                                                                        \
    _Pragma("unroll")                                                        \
    for (int it = 0; it < 4; ++it)                                           \
        rb[it] = *(const float4*)(bp2[it] + (K0));

#define G2_WRITE()                                                           \
    _Pragma("unroll")                                                        \
    for (int it = 0; it < 4; ++it)                                           \
        *(u16x8*)(As2 + swz((tid >> 3) + it * 64, acb)) = raa[it];           \
    _Pragma("unroll")                                                        \
    for (int it = 0; it < 4; ++it)                                           \
        *(bf16x4*)(Bs2 + swz(sr + it * 32, scb)) = cvt4(rb[it]);

#define G2_MFMA()                                                            \
    _Pragma("unroll")                                                        \
    for (int kk = 0; kk < 2; ++kk) {                                         \
        int kb = kk * 64 + lk * 16;                                          \
        bf16x8 af[4], bfederated[4];                                         \
        _Pragma("unroll")                                                    \
        for (int i = 0; i < 4; ++i) {                                        \
            af[i] = *(const bf16x8*)(As2 + swz(wm * 64 + i * 16 + lrow, kb));\
            bederated:;                                                      \
        }                                                                    \
    }

#undef G2_MFMA
#define G2_MFMA()                                                            \
    _Pragma("unroll")                                                        \
    for (int kk = 0; kk < 2; ++kk) {                                         \
        int kb = kk * 64 + lk * 16;                                          \
        bf16x8 af[4], bf[4];                                                 \
        _Pragma("unroll")                                                    \
        for (int i = 0; i < 4; ++i) {                                        \
            af[i] = *(const bf16x8*)(As2 + swz(wm * 64 + i * 16 + lrow, kb)); \
            bf[i] = *(const bf16x8*)(Bs2 + swz(wn * 64 + i * 16 + lrow, kb)); \
        }                                                                    \
        _Pragma("unroll")                                                    \
        for (int fm = 0; fm < 4; ++fm)                                       \
            _Pragma("unroll")                                                \
            for (int fn = 0; fn < 4; ++fn)                                   \
                acc[fm][fn] = __builtin_amdgcn_mfma_f32_16x16x32_bf16(af[fm], bf[fn], acc[fm][fn], 0, 0, 0); \
    }

__global__ __launch_bounds__(512) void moe_gemm2(
        const u16* __restrict__ act, const float* __restrict__ w2,
        const int* __restrict__ mi, const float* __restrict__ mf,
        float* __restrict__ out) {
    const int tj = blockIdx.x, ct = blockIdx.y, kz = blockIdx.z;  // ct 0..15
    if (tj >= mi[16]) return;
    const int e = mi[32 + 2 * tj], row_base = mi[32 + 2 * tj + 1];
    const int* rowtok = mi + 2560;
    const float* roww = mf + 5632;
    const int limit = mi[24 + e] + (((mi[e] + 63) >> 6) << 6);

    __shared__ __align__(16) char smem[49152];
    char* As2 = smem;
    char* Bs2 = smem + 32768;

    const int tid = threadIdx.x;
    const int w = tid >> 6, lane = tid & 63;
    const int wm = w >> 1, wn = w & 1;
    const int lrow = lane & 15, lk = lane >> 4;

    const int sr  = tid >> 4;          // 0..31
    const int sc  = (tid & 15) * 4;
    const int scb = (tid & 15) * 8;
    const int ac  = (tid & 7) * 8;
    const int acb = (tid & 7) * 16;
    const int kbeg = kz * KCH, kend = kbeg + KCH;

    const u16* ap2[4];
#pragma unroll
    for (int it = 0; it < 4; ++it) {
        int slot = row_base + (tid >> 3) + it * 64;
        bool ok = (slot < limit) && (rowtok[slot] >= 0);
        ap2[it] = ok ? act + (size_t)slot * INTER + ac : nullptr;
    }
    const float* b_base = w2 + ((size_t)e * HID + (size_t)ct * 128) * INTER;
    const float* bp2[4];
#pragma unroll
    for (int it = 0; it < 4; ++it)
        bp2[it] = b_base + (size_t)(sr + it * 32) * INTER + sc;

    f32x4 acc[4][4] = {};
    u16x8 raa[4]; float4 rb[4];

    G2_LOAD(kbeg)
    G2_WRITE()
    __syncthreads();
    for (int k0 = kbeg + BK; k0 <= kend; k0 += BK) {
        const bool more = k0 < kend;
        if (more) { G2_LOAD(k0) }
        G2_MFMA()
        __syncthreads();
        if (more) { G2_WRITE() __syncthreads(); }
    }

#pragma unroll
    for (int fm = 0; fm < 4; ++fm)
#pragma unroll
    for (int fn = 0; fn < 4; ++fn)
#pragma unroll
    for (int j = 0; j < 4; ++j) {
        int row = wm * 64 + fm * 16 + lk * 4 + j;
        int col = wn * 64 + fn * 16 + lrow;
        int slot = row_base + row;
        if (slot < limit) {
            int tok = rowtok[slot];
            if (tok >= 0)
                atomicAdd(out + (size_t)tok * HID + (size_t)ct * 128 + col,
                          acc[fm][fn][j] * roww[slot]);
        }
    }
}

extern "C" void kernel_launch(void* const* d_in, const int* in_sizes, int n_in,
                              void* d_out, int out_size, void* d_ws, size_t ws_size,
                              hipStream_t stream) {
    const float* hidden = (const float*)d_in[0];
    const float* logits = (const float*)d_in[1];
    const float* w13    = (const float*)d_in[2];
    const float* w2     = (const float*)d_in[3];
    float* out = (float*)d_out;

    int*   mi  = (int*)d_ws;
    float* mf  = (float*)d_ws;
    u16*   act = (u16*)((char*)d_ws + 65536);
    u16*   hpk = (u16*)((char*)d_ws + 33554432);

    hipMemsetAsync(d_ws, 0, 64, stream);
    hipMemsetAsync(d_out, 0, (size_t)out_size * sizeof(float), stream);

    moe_pack<<<dim3(T_TOK * HID / 8 / 256), 256, 0, stream>>>(hidden, hpk);
    moe_router<<<dim3(T_TOK / 256), 256, 0, stream>>>(logits, mi, mf);
    moe_plan<<<dim3(1), 256, 0, stream>>>(mi);
    moe_scatter<<<dim3(T_TOK / 256), 256, 0, stream>>>(mi, mf);
    moe_gemm1<<<dim3(MAXT, INTER / 64), 512, 0, stream>>>(hpk, w13, mi, act);
    moe_gemm2<<<dim3(MAXT, HID / 128, INTER / KCH), 512, 0, stream>>>(act, w2, mi, mf, out);
}

// Round 12
// 507.886 us; speedup vs baseline: 1.1914x; 1.1914x over previous
//
#include <hip/hip_runtime.h>
#include <stdint.h>

#define T_TOK 1024
#define HID   2048
#define NE    8
#define INTER 5632
#define I2    11264
#define BK    64
#define MAXT  18     // worst-case sum ceil(c64/256) over experts
#define RMAX  2560
#define KCH   2816   // INTER/2, GEMM2 K-split chunk (kz=2)

typedef __bf16 bf16x8 __attribute__((ext_vector_type(8)));
typedef __bf16 bf16x4 __attribute__((ext_vector_type(4)));
typedef float  f32x4  __attribute__((ext_vector_type(4)));
typedef unsigned short u16;
typedef u16 u16x8 __attribute__((ext_vector_type(8)));

// ws layout: mi/mf meta in [0,64KB); act (bf16, RMAX x INTER) at byte 65536;
// hpk (bf16, T_TOK x HID) at byte 33554432.

__device__ __forceinline__ int swz(int row, int cb) {
    return row * 128 + (cb ^ ((row & 7) << 4));
}

__device__ __forceinline__ bf16x4 cvt4(float4 v) {
    bf16x4 r;
    r[0] = (__bf16)v.x; r[1] = (__bf16)v.y; r[2] = (__bf16)v.z; r[3] = (__bf16)v.w;
    return r;
}

__global__ __launch_bounds__(256) void moe_pack(const float* __restrict__ h,
                                                u16* __restrict__ hpk) {
    int i = blockIdx.x * blockDim.x + threadIdx.x;
    float4 a = ((const float4*)h)[2 * i];
    float4 b = ((const float4*)h)[2 * i + 1];
    bf16x8 o;
    o[0] = (__bf16)a.x; o[1] = (__bf16)a.y; o[2] = (__bf16)a.z; o[3] = (__bf16)a.w;
    o[4] = (__bf16)b.x; o[5] = (__bf16)b.y; o[6] = (__bf16)b.z; o[7] = (__bf16)b.w;
    ((bf16x8*)hpk)[i] = o;
}

__global__ void moe_router(const float* __restrict__ logits,
                           int* __restrict__ mi, float* __restrict__ mf) {
    int t = blockIdx.x * blockDim.x + threadIdx.x;
    if (t >= T_TOK) return;
    float l[NE];
#pragma unroll
    for (int i = 0; i < NE; ++i) l[i] = logits[t * NE + i];
    int e0 = 0; float v0 = l[0];
#pragma unroll
    for (int i = 1; i < NE; ++i) if (l[i] > v0) { v0 = l[i]; e0 = i; }
    int e1 = -1; float v1 = -3.4e38f;
#pragma unroll
    for (int i = 0; i < NE; ++i) if (i != e0 && l[i] > v1) { v1 = l[i]; e1 = i; }
    float ex = __expf(v1 - v0);
    float s  = 1.f + ex;
    mi[256 + 2 * t]     = e0;
    mi[256 + 2 * t + 1] = e1;
    mf[8192 + 2 * t]     = 1.f / s;
    mf[8192 + 2 * t + 1] = ex / s;
    atomicAdd(&mi[e0], 1);
    atomicAdd(&mi[e1], 1);
}

__global__ void moe_plan(int* __restrict__ mi) {
    int tid = threadIdx.x;
    if (tid == 0) {
        int off = 0, nt = 0;
        for (int e = 0; e < NE; ++e) {
            int c = mi[e];
            mi[24 + e] = off;
            int c64 = ((c + 63) >> 6) << 6;          // 64-padded slot region
            int ntile = (c64 + 255) >> 8;            // 256-row tiles
            for (int j = 0; j < ntile; ++j) {
                mi[32 + 2 * nt]     = e;
                mi[32 + 2 * nt + 1] = off + j * 256;
                ++nt;
            }
            off += c64;
            mi[8 + e] = 0;
        }
        mi[16] = nt;
    }
    for (int i = tid; i < RMAX; i += blockDim.x) mi[2560 + i] = -1;
}

__global__ void moe_scatter(int* __restrict__ mi, float* __restrict__ mf) {
    int t = blockIdx.x * blockDim.x + threadIdx.x;
    if (t >= T_TOK) return;
    int e0 = mi[256 + 2 * t], e1 = mi[256 + 2 * t + 1];
    float w0 = mf[8192 + 2 * t], w1 = mf[8192 + 2 * t + 1];
    int p0 = atomicAdd(&mi[8 + e0], 1);
    int s0 = mi[24 + e0] + p0;
    mi[2560 + s0] = t; mf[5632 + s0] = w0;
    int p1 = atomicAdd(&mi[8 + e1], 1);
    int s1 = mi[24 + e1] + p1;
    mi[2560 + s1] = t; mf[5632 + s1] = w1;
}

// ---- GEMM1: 256x(64g+64u) tile per block, 512 threads, 2-phase pipeline ----
// merged LDS: As @0 (32KB bf16), Bg @32768 (8KB), Bu @40960 (8KB), toks @49152
// grid: 1584 blocks 1D, bijective XCD swizzle, tj-fastest after decode.

#define G1_LOAD(K0)                                                          \
    _Pragma("unroll")                                                        \
    for (int it = 0; it < 4; ++it) {                                         \
        u16x8 z = {};                                                        \
        raa[it] = ap1[it] ? *(const u16x8*)(ap1[it] + (K0)) : z;             \
    }                                                                        \
    _Pragma("unroll")                                                        \
    for (int it = 0; it < 2; ++it) {                                         \
        rg[it] = *(const float4*)(bgp[it] + (K0));                           \
        ru[it] = *(const float4*)(bup[it] + (K0));                           \
    }

#define G1_WRITE()                                                           \
    _Pragma("unroll")                                                        \
    for (int it = 0; it < 4; ++it)                                           \
        *(u16x8*)(As + swz((tid >> 3) + it * 64, acb)) = raa[it];            \
    _Pragma("unroll")                                                        \
    for (int it = 0; it < 2; ++it) {                                         \
        *(bf16x4*)(Bgs + swz(sr + it * 32, scb)) = cvt4(rg[it]);             \
        *(bf16x4*)(Bus + swz(sr + it * 32, scb)) = cvt4(ru[it]);             \
    }

#define G1_MFMA()                                                            \
    _Pragma("unroll")                                                        \
    for (int kk = 0; kk < 2; ++kk) {                                         \
        int kb = kk * 64 + lk * 16;                                          \
        bf16x8 a0 = *(const bf16x8*)(As + swz(w * 32 + lrow, kb));           \
        bf16x8 a1 = *(const bf16x8*)(As + swz(w * 32 + 16 + lrow, kb));      \
        _Pragma("unroll")                                                    \
        for (int fn = 0; fn < 4; ++fn) {                                     \
            bf16x8 bg = *(const bf16x8*)(Bgs + swz(fn * 16 + lrow, kb));     \
            bf16x8 bu = *(const bf16x8*)(Bus + swz(fn * 16 + lrow, kb));     \
            accg[0][fn] = __builtin_amdgcn_mfma_f32_16x16x32_bf16(a0, bg, accg[0][fn], 0, 0, 0); \
            accg[1][fn] = __builtin_amdgcn_mfma_f32_16x16x32_bf16(a1, bg, accg[1][fn], 0, 0, 0); \
            accu[0][fn] = __builtin_amdgcn_mfma_f32_16x16x32_bf16(a0, bu, accu[0][fn], 0, 0, 0); \
            accu[1][fn] = __builtin_amdgcn_mfma_f32_16x16x32_bf16(a1, bu, accu[1][fn], 0, 0, 0); \
        }                                                                    \
    }

__global__ __launch_bounds__(512) void moe_gemm1(
        const u16* __restrict__ hpk, const float* __restrict__ w13,
        const int* __restrict__ mi, u16* __restrict__ act) {
    // bijective XCD swizzle: nwg=1584=8*198
    const int bid = blockIdx.x;
    const int s   = (bid & 7) * 198 + (bid >> 3);
    const int tj  = s % MAXT;
    const int ct  = s / MAXT;                     // 0..87
    if (tj >= mi[16]) return;
    const int e = mi[32 + 2 * tj], row_base = mi[32 + 2 * tj + 1];
    const int* rowtok = mi + 2560;
    const int limit = mi[24 + e] + (((mi[e] + 63) >> 6) << 6);

    __shared__ __align__(16) char smem[50176];
    char* As  = smem;
    char* Bgs = smem + 32768;
    char* Bus = smem + 40960;
    int*  toks = (int*)(smem + 49152);

    const int tid = threadIdx.x;
    const int w = tid >> 6, lane = tid & 63;
    const int lrow = lane & 15, lk = lane >> 4;

    const int sr  = tid >> 4;          // B staging: 0..31
    const int sc  = (tid & 15) * 4;
    const int scb = (tid & 15) * 8;
    const int acb = (tid & 7) * 16;    // A staging byte col

    if (tid < 256) {
        int idx = row_base + tid;
        toks[tid] = (idx < limit) ? rowtok[idx] : -1;
    }
    __syncthreads();

    const u16* ap1[4];
#pragma unroll
    for (int it = 0; it < 4; ++it) {
        int tok = toks[(tid >> 3) + it * 64];
        ap1[it] = (tok >= 0) ? hpk + (size_t)tok * HID + (tid & 7) * 8 : nullptr;
    }
    const float* bg_base = w13 + ((size_t)e * I2 + (size_t)ct * 64) * HID;
    const float* bu_base = bg_base + (size_t)INTER * HID;
    const float* bgp[2];
    const float* bup[2];
#pragma unroll
    for (int it = 0; it < 2; ++it) {
        bgp[it] = bg_base + (size_t)(sr + it * 32) * HID + sc;
        bup[it] = bu_base + (size_t)(sr + it * 32) * HID + sc;
    }

    f32x4 accg[2][4] = {}, accu[2][4] = {};
    u16x8 raa[4]; float4 rg[2], ru[2];

    G1_LOAD(0)
    G1_WRITE()
    __syncthreads();
    for (int k0 = BK; k0 <= HID; k0 += BK) {
        const bool more = k0 < HID;
        if (more) { G1_LOAD(k0) }
        G1_MFMA()
        __syncthreads();
        if (more) { G1_WRITE() __syncthreads(); }
    }

    const size_t actbase = (size_t)row_base * INTER + (size_t)ct * 64;
#pragma unroll
    for (int fm = 0; fm < 2; ++fm)
#pragma unroll
    for (int fn = 0; fn < 4; ++fn)
#pragma unroll
    for (int j = 0; j < 4; ++j) {
        int row = w * 32 + fm * 16 + lk * 4 + j;
        int col = fn * 16 + lrow;
        if (toks[row] >= 0) {
            float g = accg[fm][fn][j], u = accu[fm][fn][j];
            float a = g / (1.f + __expf(-g)) * u;
            ((__bf16*)act)[actbase + (size_t)row * INTER + col] = (__bf16)a;
        }
    }
}

// ---- GEMM2: 256x64 tile, 512 threads, K-split kz=2, XCD-swizzled grid ------
// merged LDS: As2 @0 (32KB bf16), Bs2 @32768 (8KB)

#define G2_LOAD(K0)                                                          \
    _Pragma("unroll")                                                        \
    for (int it = 0; it < 4; ++it) {                                         \
        u16x8 z = {};                                                        \
        raa[it] = ap2[it] ? *(const u16x8*)(ap2[it] + (K0)) : z;             \
    }                                                                        \
    _Pragma("unroll")                                                        \
    for (int it = 0; it < 2; ++it)                                           \
        rb[it] = *(const float4*)(bp2[it] + (K0));

#define G2_WRITE()                                                           \
    _Pragma("unroll")                                                        \
    for (int it = 0; it < 4; ++it)                                           \
        *(u16x8*)(As2 + swz((tid >> 3) + it * 64, acb)) = raa[it];           \
    _Pragma("unroll")                                                        \
    for (int it = 0; it < 2; ++it)                                           \
        *(bf16x4*)(Bs2 + swz(sr + it * 32, scb)) = cvt4(rb[it]);

#define G2_MFMA()                                                            \
    _Pragma("unroll")                                                        \
    for (int kk = 0; kk < 2; ++kk) {                                         \
        int kb = kk * 64 + lk * 16;                                          \
        bf16x8 a0 = *(const bf16x8*)(As2 + swz(w * 32 + lrow, kb));          \
        bf16x8 a1 = *(const bf16x8*)(As2 + swz(w * 32 + 16 + lrow, kb));     \
        _Pragma("unroll")                                                    \
        for (int fn = 0; fn < 4; ++fn) {                                     \
            bf16x8 b = *(const bf16x8*)(Bs2 + swz(fn * 16 + lrow, kb));      \
            acc[0][fn] = __builtin_amdgcn_mfma_f32_16x16x32_bf16(a0, b, acc[0][fn], 0, 0, 0); \
            acc[1][fn] = __builtin_amdgcn_mfma_f32_16x16x32_bf16(a1, b, acc[1][fn], 0, 0, 0); \
        }                                                                    \
    }

__global__ __launch_bounds__(512) void moe_gemm2(
        const u16* __restrict__ act, const float* __restrict__ w2,
        const int* __restrict__ mi, const float* __restrict__ mf,
        float* __restrict__ out) {
    // bijective XCD swizzle: nwg=1152=8*144
    const int bid = blockIdx.x;
    const int s   = (bid & 7) * 144 + (bid >> 3);
    const int tj  = s % MAXT;
    const int ct  = (s / MAXT) % 32;
    const int kz  = s / (MAXT * 32);              // 0..1
    if (tj >= mi[16]) return;
    const int e = mi[32 + 2 * tj], row_base = mi[32 + 2 * tj + 1];
    const int* rowtok = mi + 2560;
    const float* roww = mf + 5632;
    const int limit = mi[24 + e] + (((mi[e] + 63) >> 6) << 6);

    __shared__ __align__(16) char smem[40960];
    char* As2 = smem;
    char* Bs2 = smem + 32768;

    const int tid = threadIdx.x;
    const int w = tid >> 6, lane = tid & 63;
    const int lrow = lane & 15, lk = lane >> 4;

    const int sr  = tid >> 4;
    const int sc  = (tid & 15) * 4;
    const int scb = (tid & 15) * 8;
    const int ac  = (tid & 7) * 8;
    const int acb = (tid & 7) * 16;
    const int kbeg = kz * KCH, kend = kbeg + KCH;

    const u16* ap2[4];
#pragma unroll
    for (int it = 0; it < 4; ++it) {
        int slot = row_base + (tid >> 3) + it * 64;
        bool ok = (slot < limit) && (rowtok[slot] >= 0);
        ap2[it] = ok ? act + (size_t)slot * INTER + ac : nullptr;
    }
    const float* b_base = w2 + ((size_t)e * HID + (size_t)ct * 64) * INTER;
    const float* bp2[2];
#pragma unroll
    for (int it = 0; it < 2; ++it)
        bp2[it] = b_base + (size_t)(sr + it * 32) * INTER + sc;

    f32x4 acc[2][4] = {};
    u16x8 raa[4]; float4 rb[2];

    G2_LOAD(kbeg)
    G2_WRITE()
    __syncthreads();
    for (int k0 = kbeg + BK; k0 <= kend; k0 += BK) {
        const bool more = k0 < kend;
        if (more) { G2_LOAD(k0) }
        G2_MFMA()
        __syncthreads();
        if (more) { G2_WRITE() __syncthreads(); }
    }

#pragma unroll
    for (int fm = 0; fm < 2; ++fm)
#pragma unroll
    for (int fn = 0; fn < 4; ++fn)
#pragma unroll
    for (int j = 0; j < 4; ++j) {
        int row = w * 32 + fm * 16 + lk * 4 + j;
        int col = fn * 16 + lrow;
        int slot = row_base + row;
        if (slot < limit) {
            int tok = rowtok[slot];
            if (tok >= 0)
                atomicAdd(out + (size_t)tok * HID + (size_t)ct * 64 + col,
                          acc[fm][fn][j] * roww[slot]);
        }
    }
}

extern "C" void kernel_launch(void* const* d_in, const int* in_sizes, int n_in,
                              void* d_out, int out_size, void* d_ws, size_t ws_size,
                              hipStream_t stream) {
    const float* hidden = (const float*)d_in[0];
    const float* logits = (const float*)d_in[1];
    const float* w13    = (const float*)d_in[2];
    const float* w2     = (const float*)d_in[3];
    float* out = (float*)d_out;

    int*   mi  = (int*)d_ws;
    float* mf  = (float*)d_ws;
    u16*   act = (u16*)((char*)d_ws + 65536);
    u16*   hpk = (u16*)((char*)d_ws + 33554432);

    hipMemsetAsync(d_ws, 0, 64, stream);
    hipMemsetAsync(d_out, 0, (size_t)out_size * sizeof(float), stream);

    moe_pack<<<dim3(T_TOK * HID / 8 / 256), 256, 0, stream>>>(hidden, hpk);
    moe_router<<<dim3(T_TOK / 256), 256, 0, stream>>>(logits, mi, mf);
    moe_plan<<<dim3(1), 256, 0, stream>>>(mi);
    moe_scatter<<<dim3(T_TOK / 256), 256, 0, stream>>>(mi, mf);
    moe_gemm1<<<dim3(MAXT * (INTER / 64)), 512, 0, stream>>>(hpk, w13, mi, act);
    moe_gemm2<<<dim3(MAXT * (HID / 64) * 2), 512, 0, stream>>>(act, w2, mi, mf, out);
}

// Round 13
// 493.964 us; speedup vs baseline: 1.2250x; 1.0282x over previous
//
#include <hip/hip_runtime.h>
#include <stdint.h>

#define T_TOK 1024
#define HID   2048
#define NE    8
#define INTER 5632
#define I2    11264
#define BK    64
#define MAXT  18     // worst-case sum ceil(c64/256) over experts
#define RMAX  2560
#define KCH   2816   // INTER/2, GEMM2 K-split chunk (kz=2)

typedef __bf16 bf16x8 __attribute__((ext_vector_type(8)));
typedef __bf16 bf16x4 __attribute__((ext_vector_type(4)));
typedef float  f32x4  __attribute__((ext_vector_type(4)));
typedef unsigned short u16;
typedef u16 u16x8 __attribute__((ext_vector_type(8)));

// ws layout: mi/mf meta in [0,64KB); act (bf16, RMAX x INTER) at byte 65536;
// hpk (bf16, T_TOK x HID) at byte 33554432.

__device__ __forceinline__ int swz(int row, int cb) {
    return row * 128 + (cb ^ ((row & 7) << 4));
}

__device__ __forceinline__ bf16x4 cvt4(float4 v) {
    bf16x4 r;
    r[0] = (__bf16)v.x; r[1] = (__bf16)v.y; r[2] = (__bf16)v.z; r[3] = (__bf16)v.w;
    return r;
}

__global__ __launch_bounds__(256) void moe_pack(const float* __restrict__ h,
                                                u16* __restrict__ hpk) {
    int i = blockIdx.x * blockDim.x + threadIdx.x;
    float4 a = ((const float4*)h)[2 * i];
    float4 b = ((const float4*)h)[2 * i + 1];
    bf16x8 o;
    o[0] = (__bf16)a.x; o[1] = (__bf16)a.y; o[2] = (__bf16)a.z; o[3] = (__bf16)a.w;
    o[4] = (__bf16)b.x; o[5] = (__bf16)b.y; o[6] = (__bf16)b.z; o[7] = (__bf16)b.w;
    ((bf16x8*)hpk)[i] = o;
}

__global__ void moe_router(const float* __restrict__ logits,
                           int* __restrict__ mi, float* __restrict__ mf) {
    int t = blockIdx.x * blockDim.x + threadIdx.x;
    if (t >= T_TOK) return;
    float l[NE];
#pragma unroll
    for (int i = 0; i < NE; ++i) l[i] = logits[t * NE + i];
    int e0 = 0; float v0 = l[0];
#pragma unroll
    for (int i = 1; i < NE; ++i) if (l[i] > v0) { v0 = l[i]; e0 = i; }
    int e1 = -1; float v1 = -3.4e38f;
#pragma unroll
    for (int i = 0; i < NE; ++i) if (i != e0 && l[i] > v1) { v1 = l[i]; e1 = i; }
    float ex = __expf(v1 - v0);
    float s  = 1.f + ex;
    mi[256 + 2 * t]     = e0;
    mi[256 + 2 * t + 1] = e1;
    mf[8192 + 2 * t]     = 1.f / s;
    mf[8192 + 2 * t + 1] = ex / s;
    atomicAdd(&mi[e0], 1);
    atomicAdd(&mi[e1], 1);
}

__global__ void moe_plan(int* __restrict__ mi) {
    int tid = threadIdx.x;
    if (tid == 0) {
        int off = 0, nt = 0;
        for (int e = 0; e < NE; ++e) {
            int c = mi[e];
            mi[24 + e] = off;
            int c64 = ((c + 63) >> 6) << 6;          // 64-padded slot region
            int ntile = (c64 + 255) >> 8;            // 256-row tiles
            for (int j = 0; j < ntile; ++j) {
                mi[32 + 2 * nt]     = e;
                mi[32 + 2 * nt + 1] = off + j * 256;
                ++nt;
            }
            off += c64;
            mi[8 + e] = 0;
        }
        mi[16] = nt;
    }
    for (int i = tid; i < RMAX; i += blockDim.x) mi[2560 + i] = -1;
}

__global__ void moe_scatter(int* __restrict__ mi, float* __restrict__ mf) {
    int t = blockIdx.x * blockDim.x + threadIdx.x;
    if (t >= T_TOK) return;
    int e0 = mi[256 + 2 * t], e1 = mi[256 + 2 * t + 1];
    float w0 = mf[8192 + 2 * t], w1 = mf[8192 + 2 * t + 1];
    int p0 = atomicAdd(&mi[8 + e0], 1);
    int s0 = mi[24 + e0] + p0;
    mi[2560 + s0] = t; mf[5632 + s0] = w0;
    int p1 = atomicAdd(&mi[8 + e1], 1);
    int s1 = mi[24 + e1] + p1;
    mi[2560 + s1] = t; mf[5632 + s1] = w1;
}

// ---- GEMM1: 256x(128g+128u) tile, 1024 threads (8wm x 2wn), 2-phase --------
// merged LDS: As @0 (32KB bf16), Bg @32768 (16KB), Bu @49152 (16KB), toks @65536
// grid: 792 blocks 1D = 8*99, bijective XCD swizzle, tj-fastest after decode.

#define G1_LOAD(K0)                                                          \
    _Pragma("unroll")                                                        \
    for (int it = 0; it < 2; ++it) {                                         \
        u16x8 z = {};                                                        \
        raa[it] = ap1[it] ? *(const u16x8*)(ap1[it] + (K0)) : z;             \
    }                                                                        \
    _Pragma("unroll")                                                        \
    for (int it = 0; it < 2; ++it) {                                         \
        rg[it] = *(const float4*)(bgp[it] + (K0));                           \
        ru[it] = *(const float4*)(bup[it] + (K0));                           \
    }

#define G1_WRITE()                                                           \
    _Pragma("unroll")                                                        \
    for (int it = 0; it < 2; ++it)                                           \
        *(u16x8*)(As + swz((tid >> 3) + it * 128, acb)) = raa[it];           \
    _Pragma("unroll")                                                        \
    for (int it = 0; it < 2; ++it) {                                         \
        *(bf16x4*)(Bgs + swz((tid >> 4) + it * 64, scb)) = cvt4(rg[it]);     \
        *(bf16x4*)(Bus + swz((tid >> 4) + it * 64, scb)) = cvt4(ru[it]);     \
    }

#define G1_MFMA()                                                            \
    _Pragma("unroll")                                                        \
    for (int kk = 0; kk < 2; ++kk) {                                         \
        int kb = kk * 64 + lk * 16;                                          \
        bf16x8 a0 = *(const bf16x8*)(As + swz(wm * 32 + lrow, kb));          \
        bf16x8 a1 = *(const bf16x8*)(As + swz(wm * 32 + 16 + lrow, kb));     \
        _Pragma("unroll")                                                    \
        for (int fn = 0; fn < 4; ++fn) {                                     \
            bf16x8 bg = *(const bf16x8*)(Bgs + swz(wn * 64 + fn * 16 + lrow, kb)); \
            bf16x8 bu = *(const bf16x8*)(Bus + swz(wn * 64 + fn * 16 + lrow, kb)); \
            accg[0][fn] = __builtin_amdgcn_mfma_f32_16x16x32_bf16(a0, bg, accg[0][fn], 0, 0, 0); \
            accg[1][fn] = __builtin_amdgcn_mfma_f32_16x16x32_bf16(a1, bg, accg[1][fn], 0, 0, 0); \
            accu[0][fn] = __builtin_amdgcn_mfma_f32_16x16x32_bf16(a0, bu, accu[0][fn], 0, 0, 0); \
            accu[1][fn] = __builtin_amdgcn_mfma_f32_16x16x32_bf16(a1, bu, accu[1][fn], 0, 0, 0); \
        }                                                                    \
    }

__global__ __launch_bounds__(1024) void moe_gemm1(
        const u16* __restrict__ hpk, const float* __restrict__ w13,
        const int* __restrict__ mi, u16* __restrict__ act) {
    // bijective XCD swizzle: nwg=792=8*99
    const int bid = blockIdx.x;
    const int s   = (bid & 7) * 99 + (bid >> 3);
    const int tj  = s % MAXT;
    const int ct  = s / MAXT;                     // 0..43
    if (tj >= mi[16]) return;
    const int e = mi[32 + 2 * tj], row_base = mi[32 + 2 * tj + 1];
    const int* rowtok = mi + 2560;
    const int limit = mi[24 + e] + (((mi[e] + 63) >> 6) << 6);

    __shared__ __align__(16) char smem[66560];
    char* As  = smem;
    char* Bgs = smem + 32768;
    char* Bus = smem + 49152;
    int*  toks = (int*)(smem + 65536);

    const int tid = threadIdx.x;
    const int w = tid >> 6, lane = tid & 63;
    const int wm = w >> 1, wn = w & 1;
    const int lrow = lane & 15, lk = lane >> 4;

    const int sc  = (tid & 15) * 4;    // B staging f32 col
    const int scb = (tid & 15) * 8;    // B staging bf16 byte col
    const int acb = (tid & 7) * 16;    // A staging byte col

    if (tid < 256) {
        int idx = row_base + tid;
        toks[tid] = (idx < limit) ? rowtok[idx] : -1;
    }
    __syncthreads();

    const u16* ap1[2];
#pragma unroll
    for (int it = 0; it < 2; ++it) {
        int tok = toks[(tid >> 3) + it * 128];
        ap1[it] = (tok >= 0) ? hpk + (size_t)tok * HID + (tid & 7) * 8 : nullptr;
    }
    const float* bg_base = w13 + ((size_t)e * I2 + (size_t)ct * 128) * HID;
    const float* bu_base = bg_base + (size_t)INTER * HID;
    const float* bgp[2];
    const float* bup[2];
#pragma unroll
    for (int it = 0; it < 2; ++it) {
        bgp[it] = bg_base + (size_t)((tid >> 4) + it * 64) * HID + sc;
        bup[it] = bu_base + (size_t)((tid >> 4) + it * 64) * HID + sc;
    }

    f32x4 accg[2][4] = {}, accu[2][4] = {};
    u16x8 raa[2]; float4 rg[2], ru[2];

    G1_LOAD(0)
    G1_WRITE()
    __syncthreads();
    for (int k0 = BK; k0 <= HID; k0 += BK) {
        const bool more = k0 < HID;
        if (more) { G1_LOAD(k0) }
        G1_MFMA()
        __syncthreads();
        if (more) { G1_WRITE() __syncthreads(); }
    }

    const size_t actbase = (size_t)row_base * INTER + (size_t)ct * 128;
#pragma unroll
    for (int fm = 0; fm < 2; ++fm)
#pragma unroll
    for (int fn = 0; fn < 4; ++fn)
#pragma unroll
    for (int j = 0; j < 4; ++j) {
        int row = wm * 32 + fm * 16 + lk * 4 + j;
        int col = wn * 64 + fn * 16 + lrow;
        if (toks[row] >= 0) {
            float g = accg[fm][fn][j], u = accu[fm][fn][j];
            float a = g / (1.f + __expf(-g)) * u;
            ((__bf16*)act)[actbase + (size_t)row * INTER + col] = (__bf16)a;
        }
    }
}

// ---- GEMM2: 256x128 tile, 1024 threads (8wm x 2wn), K-split kz=2 -----------
// merged LDS: As2 @0 (32KB bf16), Bs2 @32768 (16KB bf16)
// grid: 576 blocks 1D = 8*72, bijective XCD swizzle.

#define G2_LOAD(K0)                                                          \
    _Pragma("unroll")                                                        \
    for (int it = 0; it < 2; ++it) {                                         \
        u16x8 z = {};                                                        \
        raa[it] = ap2[it] ? *(const u16x8*)(ap2[it] + (K0)) : z;             \
    }                                                                        \
    _Pragma("unroll")                                                        \
    for (int it = 0; it < 2; ++it)                                           \
        rb[it] = *(const float4*)(bp2[it] + (K0));

#define G2_WRITE()                                                           \
    _Pragma("unroll")                                                        \
    for (int it = 0; it < 2; ++it)                                           \
        *(u16x8*)(As2 + swz((tid >> 3) + it * 128, acb)) = raa[it];          \
    _Pragma("unroll")                                                        \
    for (int it = 0; it < 2; ++it)                                           \
        *(bf16x4*)(Bs2 + swz((tid >> 4) + it * 64, scb)) = cvt4(rb[it]);

#define G2_MFMA()                                                            \
    _Pragma("unroll")                                                        \
    for (int kk = 0; kk < 2; ++kk) {                                         \
        int kb = kk * 64 + lk * 16;                                          \
        bf16x8 a0 = *(const bf16x8*)(As2 + swz(wm * 32 + lrow, kb));         \
        bf16x8 a1 = *(const bf16x8*)(As2 + swz(wm * 32 + 16 + lrow, kb));    \
        _Pragma("unroll")                                                    \
        for (int fn = 0; fn < 4; ++fn) {                                     \
            bf16x8 b = *(const bf16x8*)(Bs2 + swz(wn * 64 + fn * 16 + lrow, kb)); \
            acc[0][fn] = __builtin_amdgcn_mfma_f32_16x16x32_bf16(a0, b, acc[0][fn], 0, 0, 0); \
            acc[1][fn] = __builtin_amdgcn_mfma_f32_16x16x32_bf16(a1, b, acc[1][fn], 0, 0, 0); \
        }                                                                    \
    }

__global__ __launch_bounds__(1024) void moe_gemm2(
        const u16* __restrict__ act, const float* __restrict__ w2,
        const int* __restrict__ mi, const float* __restrict__ mf,
        float* __restrict__ out) {
    // bijective XCD swizzle: nwg=576=8*72
    const int bid = blockIdx.x;
    const int s   = (bid & 7) * 72 + (bid >> 3);
    const int tj  = s % MAXT;
    const int ct  = (s / MAXT) % 16;
    const int kz  = s / (MAXT * 16);              // 0..1
    if (tj >= mi[16]) return;
    const int e = mi[32 + 2 * tj], row_base = mi[32 + 2 * tj + 1];
    const int* rowtok = mi + 2560;
    const float* roww = mf + 5632;
    const int limit = mi[24 + e] + (((mi[e] + 63) >> 6) << 6);

    __shared__ __align__(16) char smem[49152];
    char* As2 = smem;
    char* Bs2 = smem + 32768;

    const int tid = threadIdx.x;
    const int w = tid >> 6, lane = tid & 63;
    const int wm = w >> 1, wn = w & 1;
    const int lrow = lane & 15, lk = lane >> 4;

    const int sc  = (tid & 15) * 4;
    const int scb = (tid & 15) * 8;
    const int ac  = (tid & 7) * 8;
    const int acb = (tid & 7) * 16;
    const int kbeg = kz * KCH, kend = kbeg + KCH;

    const u16* ap2[2];
#pragma unroll
    for (int it = 0; it < 2; ++it) {
        int slot = row_base + (tid >> 3) + it * 128;
        bool ok = (slot < limit) && (rowtok[slot] >= 0);
        ap2[it] = ok ? act + (size_t)slot * INTER + ac : nullptr;
    }
    const float* b_base = w2 + ((size_t)e * HID + (size_t)ct * 128) * INTER;
    const float* bp2[2];
#pragma unroll
    for (int it = 0; it < 2; ++it)
        bp2[it] = b_base + (size_t)((tid >> 4) + it * 64) * INTER + sc;

    f32x4 acc[2][4] = {};
    u16x8 raa[2]; float4 rb[2];

    G2_LOAD(kbeg)
    G2_WRITE()
    __syncthreads();
    for (int k0 = kbeg + BK; k0 <= kend; k0 += BK) {
        const bool more = k0 < kend;
        if (more) { G2_LOAD(k0) }
        G2_MFMA()
        __syncthreads();
        if (more) { G2_WRITE() __syncthreads(); }
    }

#pragma unroll
    for (int fm = 0; fm < 2; ++fm)
#pragma unroll
    for (int fn = 0; fn < 4; ++fn)
#pragma unroll
    for (int j = 0; j < 4; ++j) {
        int row = wm * 32 + fm * 16 + lk * 4 + j;
        int col = wn * 64 + fn * 16 + lrow;
        int slot = row_base + row;
        if (slot < limit) {
            int tok = rowtok[slot];
            if (tok >= 0)
                atomicAdd(out + (size_t)tok * HID + (size_t)ct * 128 + col,
                          acc[fm][fn][j] * roww[slot]);
        }
    }
}

extern "C" void kernel_launch(void* const* d_in, const int* in_sizes, int n_in,
                              void* d_out, int out_size, void* d_ws, size_t ws_size,
                              hipStream_t stream) {
    const float* hidden = (const float*)d_in[0];
    const float* logits = (const float*)d_in[1];
    const float* w13    = (const float*)d_in[2];
    const float* w2     = (const float*)d_in[3];
    float* out = (float*)d_out;

    int*   mi  = (int*)d_ws;
    float* mf  = (float*)d_ws;
    u16*   act = (u16*)((char*)d_ws + 65536);
    u16*   hpk = (u16*)((char*)d_ws + 33554432);

    hipMemsetAsync(d_ws, 0, 64, stream);
    hipMemsetAsync(d_out, 0, (size_t)out_size * sizeof(float), stream);

    moe_pack<<<dim3(T_TOK * HID / 8 / 256), 256, 0, stream>>>(hidden, hpk);
    moe_router<<<dim3(T_TOK / 256), 256, 0, stream>>>(logits, mi, mf);
    moe_plan<<<dim3(1), 256, 0, stream>>>(mi);
    moe_scatter<<<dim3(T_TOK / 256), 256, 0, stream>>>(mi, mf);
    moe_gemm1<<<dim3(MAXT * (INTER / 128)), 1024, 0, stream>>>(hpk, w13, mi, act);
    moe_gemm2<<<dim3(MAXT * (HID / 128) * 2), 1024, 0, stream>>>(act, w2, mi, mf, out);
}

// Round 14
// 479.562 us; speedup vs baseline: 1.2618x; 1.0300x over previous
//
#include <hip/hip_runtime.h>
#include <stdint.h>

#define T_TOK 1024
#define HID   2048
#define NE    8
#define INTER 5632
#define I2    11264
#define BK    64
#define MAXT  18     // worst-case sum ceil(c64/256) over experts
#define RMAX  2560
#define KCH   2816   // INTER/2, GEMM2 K-split chunk (kz=2)

typedef __bf16 bf16x8 __attribute__((ext_vector_type(8)));
typedef __bf16 bf16x4 __attribute__((ext_vector_type(4)));
typedef float  f32x4  __attribute__((ext_vector_type(4)));
typedef unsigned short u16;
typedef u16 u16x8 __attribute__((ext_vector_type(8)));

#define SBAR __builtin_amdgcn_s_barrier
#define SCHB __builtin_amdgcn_sched_barrier

// ws layout: mi/mf meta in [0,64KB); act (bf16, RMAX x INTER) at byte 65536;
// hpk (bf16, T_TOK x HID) at byte 33554432.

__device__ __forceinline__ int swz(int row, int cb) {
    return row * 128 + (cb ^ ((row & 7) << 4));
}

__device__ __forceinline__ bf16x4 cvt4(float4 v) {
    bf16x4 r;
    r[0] = (__bf16)v.x; r[1] = (__bf16)v.y; r[2] = (__bf16)v.z; r[3] = (__bf16)v.w;
    return r;
}

__global__ __launch_bounds__(256) void moe_pack(const float* __restrict__ h,
                                                u16* __restrict__ hpk) {
    int i = blockIdx.x * blockDim.x + threadIdx.x;
    float4 a = ((const float4*)h)[2 * i];
    float4 b = ((const float4*)h)[2 * i + 1];
    bf16x8 o;
    o[0] = (__bf16)a.x; o[1] = (__bf16)a.y; o[2] = (__bf16)a.z; o[3] = (__bf16)a.w;
    o[4] = (__bf16)b.x; o[5] = (__bf16)b.y; o[6] = (__bf16)b.z; o[7] = (__bf16)b.w;
    ((bf16x8*)hpk)[i] = o;
}

__global__ void moe_router(const float* __restrict__ logits,
                           int* __restrict__ mi, float* __restrict__ mf) {
    int t = blockIdx.x * blockDim.x + threadIdx.x;
    if (t >= T_TOK) return;
    float l[NE];
#pragma unroll
    for (int i = 0; i < NE; ++i) l[i] = logits[t * NE + i];
    int e0 = 0; float v0 = l[0];
#pragma unroll
    for (int i = 1; i < NE; ++i) if (l[i] > v0) { v0 = l[i]; e0 = i; }
    int e1 = -1; float v1 = -3.4e38f;
#pragma unroll
    for (int i = 0; i < NE; ++i) if (i != e0 && l[i] > v1) { v1 = l[i]; e1 = i; }
    float ex = __expf(v1 - v0);
    float s  = 1.f + ex;
    mi[256 + 2 * t]     = e0;
    mi[256 + 2 * t + 1] = e1;
    mf[8192 + 2 * t]     = 1.f / s;
    mf[8192 + 2 * t + 1] = ex / s;
    atomicAdd(&mi[e0], 1);
    atomicAdd(&mi[e1], 1);
}

__global__ void moe_plan(int* __restrict__ mi) {
    int tid = threadIdx.x;
    if (tid == 0) {
        int off = 0, nt = 0;
        for (int e = 0; e < NE; ++e) {
            int c = mi[e];
            mi[24 + e] = off;
            int c64 = ((c + 63) >> 6) << 6;          // 64-padded slot region
            int ntile = (c64 + 255) >> 8;            // 256-row tiles
            for (int j = 0; j < ntile; ++j) {
                mi[32 + 2 * nt]     = e;
                mi[32 + 2 * nt + 1] = off + j * 256;
                ++nt;
            }
            off += c64;
            mi[8 + e] = 0;
        }
        mi[16] = nt;
    }
    for (int i = tid; i < RMAX; i += blockDim.x) mi[2560 + i] = -1;
}

__global__ void moe_scatter(int* __restrict__ mi, float* __restrict__ mf) {
    int t = blockIdx.x * blockDim.x + threadIdx.x;
    if (t >= T_TOK) return;
    int e0 = mi[256 + 2 * t], e1 = mi[256 + 2 * t + 1];
    float w0 = mf[8192 + 2 * t], w1 = mf[8192 + 2 * t + 1];
    int p0 = atomicAdd(&mi[8 + e0], 1);
    int s0 = mi[24 + e0] + p0;
    mi[2560 + s0] = t; mf[5632 + s0] = w0;
    int p1 = atomicAdd(&mi[8 + e1], 1);
    int s1 = mi[24 + e1] + p1;
    mi[2560 + s1] = t; mf[5632 + s1] = w1;
}

// ---- GEMM1: 256x(128g+128u) tile, 1024 threads (8wm x 2wn), 2-phase --------
// merged LDS: As @0 (32KB bf16), Bg @32768 (16KB), Bu @49152 (16KB), toks @65536
// grid: 792 blocks 1D = 8*99, bijective XCD swizzle, tj-fastest after decode.

#define G1_LOAD(K0)                                                          \
    _Pragma("unroll")                                                        \
    for (int it = 0; it < 2; ++it) {                                         \
        u16x8 z = {};                                                        \
        raa[it] = ap1[it] ? *(const u16x8*)(ap1[it] + (K0)) : z;             \
    }                                                                        \
    _Pragma("unroll")                                                        \
    for (int it = 0; it < 2; ++it) {                                         \
        rg[it] = *(const float4*)(bgp[it] + (K0));                           \
        ru[it] = *(const float4*)(bup[it] + (K0));                           \
    }

#define G1_WRITE()                                                           \
    _Pragma("unroll")                                                        \
    for (int it = 0; it < 2; ++it)                                           \
        *(u16x8*)(As + swz((tid >> 3) + it * 128, acb)) = raa[it];           \
    _Pragma("unroll")                                                        \
    for (int it = 0; it < 2; ++it) {                                         \
        *(bf16x4*)(Bgs + swz((tid >> 4) + it * 64, scb)) = cvt4(rg[it]);     \
        *(bf16x4*)(Bus + swz((tid >> 4) + it * 64, scb)) = cvt4(ru[it]);     \
    }

#define G1_MFMA()                                                            \
    _Pragma("unroll")                                                        \
    for (int kk = 0; kk < 2; ++kk) {                                         \
        int kb = kk * 64 + lk * 16;                                          \
        bf16x8 a0 = *(const bf16x8*)(As + swz(wm * 32 + lrow, kb));          \
        bf16x8 a1 = *(const bf16x8*)(As + swz(wm * 32 + 16 + lrow, kb));     \
        _Pragma("unroll")                                                    \
        for (int fn = 0; fn < 4; ++fn) {                                     \
            bf16x8 bg = *(const bf16x8*)(Bgs + swz(wn * 64 + fn * 16 + lrow, kb)); \
            bf16x8 bu = *(const bf16x8*)(Bus + swz(wn * 64 + fn * 16 + lrow, kb)); \
            accg[0][fn] = __builtin_amdgcn_mfma_f32_16x16x32_bf16(a0, bg, accg[0][fn], 0, 0, 0); \
            accg[1][fn] = __builtin_amdgcn_mfma_f32_16x16x32_bf16(a1, bg, accg[1][fn], 0, 0, 0); \
            accu[0][fn] = __builtin_amdgcn_mfma_f32_16x16x32_bf16(a0, bu, accu[0][fn], 0, 0, 0); \
            accu[1][fn] = __builtin_amdgcn_mfma_f32_16x16x32_bf16(a1, bu, accu[1][fn], 0, 0, 0); \
        }                                                                    \
    }

__global__ __launch_bounds__(1024) void moe_gemm1(
        const u16* __restrict__ hpk, const float* __restrict__ w13,
        const int* __restrict__ mi, u16* __restrict__ act) {
    // bijective XCD swizzle: nwg=792=8*99
    const int bid = blockIdx.x;
    const int s   = (bid & 7) * 99 + (bid >> 3);
    const int tj  = s % MAXT;
    const int ct  = s / MAXT;                     // 0..43
    if (tj >= mi[16]) return;
    const int e = mi[32 + 2 * tj], row_base = mi[32 + 2 * tj + 1];
    const int* rowtok = mi + 2560;
    const int limit = mi[24 + e] + (((mi[e] + 63) >> 6) << 6);

    __shared__ __align__(16) char smem[66560];
    char* As  = smem;
    char* Bgs = smem + 32768;
    char* Bus = smem + 49152;
    int*  toks = (int*)(smem + 65536);

    const int tid = threadIdx.x;
    const int w = tid >> 6, lane = tid & 63;
    const int wm = w >> 1, wn = w & 1;
    const int lrow = lane & 15, lk = lane >> 4;

    const int sc  = (tid & 15) * 4;    // B staging f32 col
    const int scb = (tid & 15) * 8;    // B staging bf16 byte col
    const int acb = (tid & 7) * 16;    // A staging byte col

    if (tid < 256) {
        int idx = row_base + tid;
        toks[tid] = (idx < limit) ? rowtok[idx] : -1;
    }
    __syncthreads();

    const u16* ap1[2];
#pragma unroll
    for (int it = 0; it < 2; ++it) {
        int tok = toks[(tid >> 3) + it * 128];
        ap1[it] = (tok >= 0) ? hpk + (size_t)tok * HID + (tid & 7) * 8 : nullptr;
    }
    const float* bg_base = w13 + ((size_t)e * I2 + (size_t)ct * 128) * HID;
    const float* bu_base = bg_base + (size_t)INTER * HID;
    const float* bgp[2];
    const float* bup[2];
#pragma unroll
    for (int it = 0; it < 2; ++it) {
        bgp[it] = bg_base + (size_t)((tid >> 4) + it * 64) * HID + sc;
        bup[it] = bu_base + (size_t)((tid >> 4) + it * 64) * HID + sc;
    }

    f32x4 accg[2][4] = {}, accu[2][4] = {};
    u16x8 raa[2]; float4 rg[2], ru[2];

    G1_LOAD(0)
    G1_WRITE()
    __syncthreads();
    for (int k0 = BK; k0 <= HID; k0 += BK) {
        const bool more = k0 < HID;
        if (more) { G1_LOAD(k0) }
        G1_MFMA()
        __syncthreads();
        if (more) { G1_WRITE() __syncthreads(); }
    }

    const size_t actbase = (size_t)row_base * INTER + (size_t)ct * 128;
#pragma unroll
    for (int fm = 0; fm < 2; ++fm)
#pragma unroll
    for (int fn = 0; fn < 4; ++fn)
#pragma unroll
    for (int j = 0; j < 4; ++j) {
        int row = wm * 32 + fm * 16 + lk * 4 + j;
        int col = wn * 64 + fn * 16 + lrow;
        if (toks[row] >= 0) {
            float g = accg[fm][fn][j], u = accu[fm][fn][j];
            float a = g / (1.f + __expf(-g)) * u;
            ((__bf16*)act)[actbase + (size_t)row * INTER + col] = (__bf16)a;
        }
    }
}

// ---- GEMM2: 256x128 tile, 1024 threads (8wm x 2wn), K-split kz=2 -----------
// depth-2 register pipeline + raw s_barrier (loads for tile k+2 stay in
// flight across barriers; ds_write's register dataflow inserts the precise
// vmcnt wait — no full drain per K-step).
// merged LDS: As2 @0 (32KB bf16), Bs2 @32768 (16KB bf16)
// grid: 576 blocks 1D = 8*72, bijective XCD swizzle.

#define G2_LOAD_S(RA, RB, K0)                                                \
    _Pragma("unroll")                                                        \
    for (int it = 0; it < 2; ++it) {                                         \
        u16x8 z = {};                                                        \
        RA[it] = ap2[it] ? *(const u16x8*)(ap2[it] + (K0)) : z;              \
    }                                                                        \
    _Pragma("unroll")                                                        \
    for (int it = 0; it < 2; ++it)                                           \
        RB[it] = *(const float4*)(bp2[it] + (K0));

#define G2_WRITE_S(RA, RB)                                                   \
    _Pragma("unroll")                                                        \
    for (int it = 0; it < 2; ++it)                                           \
        *(u16x8*)(As2 + swz((tid >> 3) + it * 128, acb)) = RA[it];           \
    _Pragma("unroll")                                                        \
    for (int it = 0; it < 2; ++it)                                           \
        *(bf16x4*)(Bs2 + swz((tid >> 4) + it * 64, scb)) = cvt4(RB[it]);

#define G2_MFMA()                                                            \
    _Pragma("unroll")                                                        \
    for (int kk = 0; kk < 2; ++kk) {                                         \
        int kb = kk * 64 + lk * 16;                                          \
        bf16x8 a0 = *(const bf16x8*)(As2 + swz(wm * 32 + lrow, kb));         \
        bf16x8 a1 = *(const bf16x8*)(As2 + swz(wm * 32 + 16 + lrow, kb));    \
        _Pragma("unroll")                                                    \
        for (int fn = 0; fn < 4; ++fn) {                                     \
            bf16x8 b = *(const bf16x8*)(Bs2 + swz(wn * 64 + fn * 16 + lrow, kb)); \
            acc[0][fn] = __builtin_amdgcn_mfma_f32_16x16x32_bf16(a0, b, acc[0][fn], 0, 0, 0); \
            acc[1][fn] = __builtin_amdgcn_mfma_f32_16x16x32_bf16(a1, b, acc[1][fn], 0, 0, 0); \
        }                                                                    \
    }

#define BARRIER() SCHB(0); SBAR(); SCHB(0);

__global__ __launch_bounds__(1024) void moe_gemm2(
        const u16* __restrict__ act, const float* __restrict__ w2,
        const int* __restrict__ mi, const float* __restrict__ mf,
        float* __restrict__ out) {
    // bijective XCD swizzle: nwg=576=8*72
    const int bid = blockIdx.x;
    const int s   = (bid & 7) * 72 + (bid >> 3);
    const int tj  = s % MAXT;
    const int ct  = (s / MAXT) % 16;
    const int kz  = s / (MAXT * 16);              // 0..1
    if (tj >= mi[16]) return;
    const int e = mi[32 + 2 * tj], row_base = mi[32 + 2 * tj + 1];
    const int* rowtok = mi + 2560;
    const float* roww = mf + 5632;
    const int limit = mi[24 + e] + (((mi[e] + 63) >> 6) << 6);

    __shared__ __align__(16) char smem[49152];
    char* As2 = smem;
    char* Bs2 = smem + 32768;

    const int tid = threadIdx.x;
    const int w = tid >> 6, lane = tid & 63;
    const int wm = w >> 1, wn = w & 1;
    const int lrow = lane & 15, lk = lane >> 4;

    const int sc  = (tid & 15) * 4;
    const int scb = (tid & 15) * 8;
    const int ac  = (tid & 7) * 8;
    const int acb = (tid & 7) * 16;
    const int kbeg = kz * KCH;

    const u16* ap2[2];
#pragma unroll
    for (int it = 0; it < 2; ++it) {
        int slot = row_base + (tid >> 3) + it * 128;
        bool ok = (slot < limit) && (rowtok[slot] >= 0);
        ap2[it] = ok ? act + (size_t)slot * INTER + ac : nullptr;
    }
    const float* b_base = w2 + ((size_t)e * HID + (size_t)ct * 128) * INTER;
    const float* bp2[2];
#pragma unroll
    for (int it = 0; it < 2; ++it)
        bp2[it] = b_base + (size_t)((tid >> 4) + it * 64) * INTER + sc;

    f32x4 acc[2][4] = {};
    u16x8 raA[2], raB[2]; float4 rbA[2], rbB[2];

    const int NK = KCH / BK;     // 44 (even)

    // prologue: tile0 -> LDS; tile1 loads in flight in set B
    G2_LOAD_S(raA, rbA, kbeg)
    G2_WRITE_S(raA, rbA)
    G2_LOAD_S(raB, rbB, kbeg + BK)
    BARRIER()
    // invariant at loop top (k even): LDS = tile k; B holds tile k+1; A free
    for (int k = 0; k < NK - 3; k += 2) {
        G2_LOAD_S(raA, rbA, kbeg + (k + 2) * BK)   // tile k+2, in flight 2 barriers
        G2_MFMA()                                  // tile k
        BARRIER()
        G2_WRITE_S(raB, rbB)                       // tile k+1 -> LDS
        BARRIER()
        G2_LOAD_S(raB, rbB, kbeg + (k + 3) * BK)   // tile k+3
        G2_MFMA()                                  // tile k+1
        BARRIER()
        G2_WRITE_S(raA, rbA)                       // tile k+2 -> LDS
        BARRIER()
    }
    G2_MFMA()                                      // tile NK-2
    BARRIER()
    G2_WRITE_S(raB, rbB)                           // tile NK-1 -> LDS
    BARRIER()
    G2_MFMA()                                      // tile NK-1

#pragma unroll
    for (int fm = 0; fm < 2; ++fm)
#pragma unroll
    for (int fn = 0; fn < 4; ++fn)
#pragma unroll
    for (int j = 0; j < 4; ++j) {
        int row = wm * 32 + fm * 16 + lk * 4 + j;
        int col = wn * 64 + fn * 16 + lrow;
        int slot = row_base + row;
        if (slot < limit) {
            int tok = rowtok[slot];
            if (tok >= 0)
                atomicAdd(out + (size_t)tok * HID + (size_t)ct * 128 + col,
                          acc[fm][fn][j] * roww[slot]);
        }
    }
}

extern "C" void kernel_launch(void* const* d_in, const int* in_sizes, int n_in,
                              void* d_out, int out_size, void* d_ws, size_t ws_size,
                              hipStream_t stream) {
    const float* hidden = (const float*)d_in[0];
    const float* logits = (const float*)d_in[1];
    const float* w13    = (const float*)d_in[2];
    const float* w2     = (const float*)d_in[3];
    float* out = (float*)d_out;

    int*   mi  = (int*)d_ws;
    float* mf  = (float*)d_ws;
    u16*   act = (u16*)((char*)d_ws + 65536);
    u16*   hpk = (u16*)((char*)d_ws + 33554432);

    hipMemsetAsync(d_ws, 0, 64, stream);
    hipMemsetAsync(d_out, 0, (size_t)out_size * sizeof(float), stream);

    moe_pack<<<dim3(T_TOK * HID / 8 / 256), 256, 0, stream>>>(hidden, hpk);
    moe_router<<<dim3(T_TOK / 256), 256, 0, stream>>>(logits, mi, mf);
    moe_plan<<<dim3(1), 256, 0, stream>>>(mi);
    moe_scatter<<<dim3(T_TOK / 256), 256, 0, stream>>>(mi, mf);
    moe_gemm1<<<dim3(MAXT * (INTER / 128)), 1024, 0, stream>>>(hpk, w13, mi, act);
    moe_gemm2<<<dim3(MAXT * (HID / 128) * 2), 1024, 0, stream>>>(act, w2, mi, mf, out);
}